// Round 15
// baseline (127.311 us; speedup 1.0000x reference)
//
#include <hip/hip_runtime.h>
#include <hip/hip_fp16.h>

#define L 1600
#define C 256
#define HW 40
#define HP 56            // padded spatial (40 + 2*8)
#define HP2 (HP * HP)    // 3136
#define KW 17
#define K2 289
#define K2P 292          // K2 padded to multiple of 4 (int4 loads)
#define HEADS 8
#define NT 32            // n-columns per attn block (8 quads)
#define NTP 40           // Plds row stride (pad: float4 writes ~conflict-free)
#define NIMG 802816      // halves per padded image (256*3136)
#define NIMGU 401408     // uints per padded image
#define SCALE 0.17677669529663687f  // 32^-0.5

// workspace layout (float slots); qT reused as outT (disjoint lifetimes)
// kAll = 4 K copies (shift 0..3); vAll = 4 V copies.
#define OFF_TH 0                         // otH: 8*289*32 ints = 73984
#define OFF_TD 73984                     // otD: 8*32*292 ints = 74752
#define OFF_QT 148736                    // qT/outT: 409600 f
#define OFF_KA 558336                    // kAll: 4*802816 halves = 1605632 f
#define OFF_VA 2163968                   // vAll: 1605632 f

// QUAD-ENCODED offsets: offE = (off & ~3) + (off & 3) * NIMG.
// Reading 8B (half4) at (offE + base4) with base4 % 4 == 0 is always aligned;
// residue off%3 is served by the shifted copy, so cols n..n+3 are correct.
__global__ __launch_bounds__(256) void addr_kernel(int* __restrict__ otH,
                                                   int* __restrict__ otD) {
    int idx = blockIdx.x * 256 + threadIdx.x;   // grid = 8*292*32/256 = 292
    int h = idx / (K2P * 32);
    int rem = idx - h * (K2P * 32);
    int n1 = rem >> 5, i = rem & 31;
    int offE = 0;
    if (n1 < K2) {
        int j = n1 * 256 + h * 32 + i;
        int c = j / K2;
        int p = j - c * K2;
        int dr = p / KW;
        int off = c * HP2 + dr * HP + (p - dr * KW);
        offE = (off & ~3) + (off & 3) * NIMG;
        otH[(h * K2 + n1) * 32 + i] = offE;
    }
    otD[(h * 32 + i) * K2P + n1] = offE;
}

// Build shifted copies s=1,2,3 for K and V from copy 0 (uint = 2 halves).
__global__ __launch_bounds__(256) void shift_kernel(unsigned int* __restrict__ kA,
                                                    unsigned int* __restrict__ vA) {
    int j = blockIdx.x * 256 + threadIdx.x;          // 0 .. 2*NIMGU-1
    unsigned int* img = (j < NIMGU) ? kA : vA;
    int u = (j < NIMGU) ? j : (j - NIMGU);
    unsigned int a = img[u];
    unsigned int b = (u + 1 < NIMGU) ? img[u + 1] : 0u;
    unsigned int c = (u + 2 < NIMGU) ? img[u + 2] : 0u;
    img[1 * NIMGU + u] = (a >> 16) | (b << 16);   // s=1
    img[2 * NIMGU + u] = b;                       // s=2
    img[3 * NIMGU + u] = (b >> 16) | (c << 16);   // s=3
}

__device__ __forceinline__ float4 gload4(const __half* img, int idx) {
    uint2 u = *reinterpret_cast<const uint2*>(img + idx);   // 8B aligned
    __half2 a = *reinterpret_cast<const __half2*>(&u.x);
    __half2 b = *reinterpret_cast<const __half2*>(&u.y);
    return make_float4(__low2float(a), __high2float(a),
                       __low2float(b), __high2float(b));
}

// qkv[l, oc] = sum_c x[c, l] * w[oc, c] + b[oc]
// q (scaled) -> qT[m][l] f32;  k/v -> fp16 padded images copy 0 (verified r4-r14)
__global__ __launch_bounds__(256) void qkv_gemm(const float* __restrict__ x,
                                                const float* __restrict__ w,
                                                const float* __restrict__ bias,
                                                float* __restrict__ qT,
                                                __half* __restrict__ kimg,
                                                __half* __restrict__ vimg) {
    __shared__ float As[16][68];  // A[c][l]
    __shared__ float Bs[16][68];  // B[c][oc]
    const int l0 = blockIdx.x * 64;
    const int oc0 = blockIdx.y * 64;
    const int tid = threadIdx.x;
    const int tx = tid & 15;   // oc quad
    const int ty = tid >> 4;   // l quad
    float acc[4][4] = {};
    for (int c0 = 0; c0 < C; c0 += 16) {
#pragma unroll
        for (int i = 0; i < 4; ++i) {
            int idx = i * 256 + tid;
            int cc = idx >> 6, ll = idx & 63;
            As[cc][ll] = x[(c0 + cc) * L + l0 + ll];
        }
#pragma unroll
        for (int i = 0; i < 4; ++i) {
            int idx = i * 256 + tid;
            int cc = idx & 15, oo = idx >> 4;
            Bs[cc][oo] = w[(oc0 + oo) * C + c0 + cc];
        }
        __syncthreads();
#pragma unroll
        for (int kk = 0; kk < 16; ++kk) {
            float4 a = *(const float4*)&As[kk][ty * 4];
            float4 b = *(const float4*)&Bs[kk][tx * 4];
            float av[4] = {a.x, a.y, a.z, a.w};
            float bv[4] = {b.x, b.y, b.z, b.w};
#pragma unroll
            for (int i = 0; i < 4; ++i)
#pragma unroll
                for (int j = 0; j < 4; ++j)
                    acc[i][j] = fmaf(av[i], bv[j], acc[i][j]);
        }
        __syncthreads();
    }
    const int lbase = l0 + ty * 4;
    const int ocbase = oc0 + tx * 4;
    if (oc0 < 256) {
#pragma unroll
        for (int j = 0; j < 4; ++j) {
            int oc = ocbase + j;
            float b = bias[oc];
            float4 v = make_float4((acc[0][j] + b) * SCALE, (acc[1][j] + b) * SCALE,
                                   (acc[2][j] + b) * SCALE, (acc[3][j] + b) * SCALE);
            *(float4*)&qT[oc * L + lbase] = v;
        }
    } else {
        __half* dst = (oc0 < 512) ? kimg : vimg;
        const int cb = ocbase - ((oc0 < 512) ? 256 : 512);
#pragma unroll
        for (int i = 0; i < 4; ++i) {
            int l = lbase + i;
            int r = l / HW, s = l % HW;
            int base = (r + 8) * HP + (s + 8);
#pragma unroll
            for (int j = 0; j < 4; ++j)
                dst[(cb + j) * HP2 + base] = __float2half(acc[i][j] + bias[ocbase + j]);
        }
    }
}

// Fused attention, NT=32 cols per block (8 quads), 512 threads, grid 400 with
// bijective XCD swizzle (r12 host config). Every gather = half4 (4 n / instr).
// Phase B: 4 passes x 8 channels; lane = (quad qd=nl&7, slot=w*8+(nl>>3)).
// Phase D: lane = (qd, ch, n1-half) with LDS cross-half reduce.
__global__ __launch_bounds__(512) void attn_fused(const float* __restrict__ qT,
                                                  const __half* __restrict__ kAll,
                                                  const __half* __restrict__ vAll,
                                                  const int* __restrict__ otH,
                                                  const int* __restrict__ otD,
                                                  float* __restrict__ outT) {
    __shared__ float Plds[K2 * NTP];    // 46240 B
    __shared__ float red[16 * NT];      // 2048 B
    __shared__ float colmax[NT], invl[NT];
    __shared__ float4 redD[256];        // 4096 B
    const int bid = blockIdx.x;
    const int wgid = (bid & 7) * 50 + (bid >> 3);
    const int h = wgid & 7;
    const int n0 = (wgid >> 3) * NT;
    const int tid = threadIdx.x;
    const int w = tid >> 6, nl = tid & 63;
    const int4* otHq = (const int4*)(otH + h * (K2 * 32));

    // ---- phase B ----
    {
        const int qd = nl & 7;                            // quad
        const int slot = w * 8 + (nl >> 3);               // 0..63
        const int npb = n0 + 4 * qd;                      // %4 == 0
        const int base4 = (npb / HW) * HP + (npb % HW);   // %4 == 0
        float4 qp[8];
        for (int pass = 0; pass < 4; ++pass) {
#pragma unroll
            for (int k = 0; k < 8; ++k)
                qp[k] = *(const float4*)&qT[(h * 32 + pass * 8 + k) * L + npb];
            auto doB = [&](int n1) {
                float c0 = 0.f, c1 = 0.f, c2 = 0.f, c3 = 0.f;
                int4 oA = otHq[n1 * 8 + pass * 2];
                int4 oB = otHq[n1 * 8 + pass * 2 + 1];
                const int oo[8] = {oA.x, oA.y, oA.z, oA.w, oB.x, oB.y, oB.z, oB.w};
#pragma unroll
                for (int k = 0; k < 8; ++k) {
                    float4 kv = gload4(kAll, oo[k] + base4);
                    c0 = fmaf(qp[k].x, kv.x, c0);
                    c1 = fmaf(qp[k].y, kv.y, c1);
                    c2 = fmaf(qp[k].z, kv.z, c2);
                    c3 = fmaf(qp[k].w, kv.w, c3);
                }
                float4* pp = (float4*)&Plds[n1 * NTP + 4 * qd];
                if (pass == 0) {
                    *pp = make_float4(c0, c1, c2, c3);
                } else {
                    float4 old = *pp;
                    *pp = make_float4(old.x + c0, old.y + c1, old.z + c2, old.w + c3);
                }
            };
#pragma unroll 2
            for (int r = 0; r < 4; ++r) doB(r * 64 + slot);
            if (slot < 33) doB(256 + slot);
        }
    }
    __syncthreads();

    // ---- phase C: per-column softmax; sum pre-mask, mask post (faithful) ----
    {
        const int col = tid & 31, seg = tid >> 5;   // 16 segments
        float mx = -1e30f;
        for (int n1 = seg; n1 < K2; n1 += 16) mx = fmaxf(mx, Plds[n1 * NTP + col]);
        red[seg * NT + col] = mx;
        __syncthreads();
        if (tid < NT) {
            float m = red[tid];
            for (int s = 1; s < 16; ++s) m = fmaxf(m, red[s * NT + tid]);
            colmax[tid] = m;
        }
        __syncthreads();
        const int ncn = n0 + col;
        const int nr = ncn / HW, nc = ncn % HW;
        const float mxc = colmax[col];
        float s = 0.f;
        for (int n1 = seg; n1 < K2; n1 += 16) {
            float e = __expf(Plds[n1 * NTP + col] - mxc);
            s += e;
            int dr = n1 / KW, ds = n1 - dr * KW;
            unsigned rr = (unsigned)(nr + dr - 8), ss = (unsigned)(nc + ds - 8);
            Plds[n1 * NTP + col] = (rr < HW && ss < HW) ? e : 0.f;
        }
        red[seg * NT + col] = s;
        __syncthreads();
        if (tid < NT) {
            float t = 0.f;
            for (int s2 = 0; s2 < 16; ++s2) t += red[s2 * NT + tid];
            invl[tid] = 1.f / t;
        }
        __syncthreads();
    }

    // ---- phase D: (quad, channel, n1-half); P = LDS float4; V = half4 ----
    {
        const int qd = tid & 7;
        const int mq = (tid >> 3) & 31;
        const int hf = tid >> 8;
        const int npb = n0 + 4 * qd;
        const int base4 = (npb / HW) * HP + (npb % HW);
        const int* otDm = otD + (h * 32 + mq) * K2P;
        const int n1lo = hf ? 144 : 0;
        float4 a0 = {0,0,0,0}, a1 = {0,0,0,0}, a2 = {0,0,0,0}, a3 = {0,0,0,0};
#pragma unroll 4
        for (int t4 = 0; t4 < 36; ++t4) {
            const int nb = n1lo + t4 * 4;
            int4 o = *(const int4*)(otDm + nb);
            float4 p0 = *(const float4*)&Plds[(nb + 0) * NTP + 4 * qd];
            float4 p1 = *(const float4*)&Plds[(nb + 1) * NTP + 4 * qd];
            float4 p2 = *(const float4*)&Plds[(nb + 2) * NTP + 4 * qd];
            float4 p3 = *(const float4*)&Plds[(nb + 3) * NTP + 4 * qd];
            float4 v0 = gload4(vAll, o.x + base4);
            float4 v1 = gload4(vAll, o.y + base4);
            float4 v2 = gload4(vAll, o.z + base4);
            float4 v3 = gload4(vAll, o.w + base4);
            a0.x = fmaf(p0.x, v0.x, a0.x); a0.y = fmaf(p0.y, v0.y, a0.y);
            a0.z = fmaf(p0.z, v0.z, a0.z); a0.w = fmaf(p0.w, v0.w, a0.w);
            a1.x = fmaf(p1.x, v1.x, a1.x); a1.y = fmaf(p1.y, v1.y, a1.y);
            a1.z = fmaf(p1.z, v1.z, a1.z); a1.w = fmaf(p1.w, v1.w, a1.w);
            a2.x = fmaf(p2.x, v2.x, a2.x); a2.y = fmaf(p2.y, v2.y, a2.y);
            a2.z = fmaf(p2.z, v2.z, a2.z); a2.w = fmaf(p2.w, v2.w, a2.w);
            a3.x = fmaf(p3.x, v3.x, a3.x); a3.y = fmaf(p3.y, v3.y, a3.y);
            a3.z = fmaf(p3.z, v3.z, a3.z); a3.w = fmaf(p3.w, v3.w, a3.w);
        }
        if (hf) {   // tail n1 = 288
            float4 p = *(const float4*)&Plds[288 * NTP + 4 * qd];
            float4 v = gload4(vAll, otDm[288] + base4);
            a0.x = fmaf(p.x, v.x, a0.x); a0.y = fmaf(p.y, v.y, a0.y);
            a0.z = fmaf(p.z, v.z, a0.z); a0.w = fmaf(p.w, v.w, a0.w);
        }
        float4 acc = make_float4((a0.x + a1.x) + (a2.x + a3.x),
                                 (a0.y + a1.y) + (a2.y + a3.y),
                                 (a0.z + a1.z) + (a2.z + a3.z),
                                 (a0.w + a1.w) + (a2.w + a3.w));
        if (hf) redD[tid - 256] = acc;
        __syncthreads();
        if (!hf) {
            float4 o = redD[tid];
            float4 iv = *(const float4*)&invl[4 * qd];
            float4 ov = make_float4((acc.x + o.x) * iv.x, (acc.y + o.y) * iv.y,
                                    (acc.z + o.z) * iv.z, (acc.w + o.w) * iv.w);
            *(float4*)&outT[(h * 32 + mq) * L + npb] = ov;
        }
    }
}

// out[oc*1600 + l] = sum_c outT[c][l] * w[oc, c] + b[oc]   (verified r4/r7-r14)
__global__ __launch_bounds__(256) void proj_gemm(const float* __restrict__ aT,
                                                 const float* __restrict__ w,
                                                 const float* __restrict__ bias,
                                                 float* __restrict__ out) {
    __shared__ float As[16][68];  // A[c][l]
    __shared__ float Bs[16][68];  // B[c][oc]
    const int l0 = blockIdx.x * 64;
    const int oc0 = blockIdx.y * 64;
    const int tid = threadIdx.x;
    const int tx = tid & 15;   // oc quad
    const int ty = tid >> 4;   // l quad
    float acc[4][4] = {};      // [i: l][j: oc]
    for (int c0 = 0; c0 < C; c0 += 16) {
#pragma unroll
        for (int i = 0; i < 4; ++i) {
            int idx = i * 256 + tid;
            int cc = idx >> 6, ll = idx & 63;
            As[cc][ll] = aT[(c0 + cc) * L + l0 + ll];
        }
#pragma unroll
        for (int i = 0; i < 4; ++i) {
            int idx = i * 256 + tid;
            int cc = idx & 15, oo = idx >> 4;
            Bs[cc][oo] = w[(oc0 + oo) * C + c0 + cc];
        }
        __syncthreads();
#pragma unroll
        for (int kk = 0; kk < 16; ++kk) {
            float4 a = *(const float4*)&As[kk][ty * 4];
            float4 b = *(const float4*)&Bs[kk][tx * 4];
            float av[4] = {a.x, a.y, a.z, a.w};
            float bv[4] = {b.x, b.y, b.z, b.w};
#pragma unroll
            for (int i = 0; i < 4; ++i)
#pragma unroll
                for (int j = 0; j < 4; ++j)
                    acc[i][j] = fmaf(av[i], bv[j], acc[i][j]);
        }
        __syncthreads();
    }
    const int lbase = l0 + ty * 4;
#pragma unroll
    for (int j = 0; j < 4; ++j) {
        int oc = oc0 + tx * 4 + j;
        float bp = bias[oc];
        float4 v = make_float4(acc[0][j] + bp, acc[1][j] + bp,
                               acc[2][j] + bp, acc[3][j] + bp);
        *(float4*)&out[oc * L + lbase] = v;
    }
}

extern "C" void kernel_launch(void* const* d_in, const int* in_sizes, int n_in,
                              void* d_out, int out_size, void* d_ws, size_t ws_size,
                              hipStream_t stream) {
    const float* x      = (const float*)d_in[0];
    const float* w_qkv  = (const float*)d_in[1];
    const float* b_qkv  = (const float*)d_in[2];
    const float* w_proj = (const float*)d_in[3];
    const float* b_proj = (const float*)d_in[4];
    float* out = (float*)d_out;
    float* ws = (float*)d_ws;
    int*    otH  = (int*)(ws + OFF_TH);
    int*    otD  = (int*)(ws + OFF_TD);
    float*  qT   = ws + OFF_QT;   // reused as outT (disjoint lifetimes)
    __half* kAll = (__half*)(ws + OFF_KA);
    __half* vAll = (__half*)(ws + OFF_VA);

    // zero copy-0 K and V images (copies 1-3 are fully written by shift_kernel)
    hipMemsetAsync(kAll, 0, (size_t)NIMG * sizeof(__half), stream);
    hipMemsetAsync(vAll, 0, (size_t)NIMG * sizeof(__half), stream);
    addr_kernel<<<292, 256, 0, stream>>>(otH, otD);

    qkv_gemm<<<dim3(25, 12), 256, 0, stream>>>(x, w_qkv, b_qkv, qT, kAll, vAll);
    shift_kernel<<<(2 * NIMGU) / 256, 256, 0, stream>>>((unsigned int*)kAll,
                                                        (unsigned int*)vAll);
    attn_fused<<<400, 512, 0, stream>>>(qT, kAll, vAll, otH, otD, qT);
    proj_gemm<<<dim3(25, 4), 256, 0, stream>>>(qT, w_proj, b_proj, out);
}

// Round 16
// 110.489 us; speedup vs baseline: 1.1522x; 1.1522x over previous
//
#include <hip/hip_runtime.h>
#include <hip/hip_fp16.h>

#define L 1600
#define C 256
#define HW 40
#define HP 56            // padded spatial (40 + 2*8)
#define HP2 (HP * HP)    // 3136
#define KW 17
#define K2 289
#define K2P 292          // K2 padded to multiple of 4 (int4 loads)
#define HEADS 8
#define NT 32            // n-columns per attn block (16 pairs)
#define NIMG 802816      // halves per padded image (256*3136)
#define NIMGU 401408     // uints per padded image
#define SCALE 0.17677669529663687f  // 32^-0.5

// workspace layout (float slots); qT reused as outT (disjoint lifetimes)
// kAll = [K image | K shifted-by-1 copy]; vAll = [V image | V shifted copy]
#define OFF_TH 0                         // otH: 8*289*32 ints = 73984
#define OFF_TD 73984                     // otD: 8*32*292 ints = 74752
#define OFF_QT 148736                    // qT/outT: 409600 f
#define OFF_KA 558336                    // kAll: 2*802816 halves = 802816 f
#define OFF_VA 1361152                   // vAll: 802816 f
#define OFF_OP 2163968                   // opart: 2*256*1600 f = 819200
#define OFF_MS 2983168                   // msb: 2*8*1600 float2 = 51200 f

// Tables with PARITY-ENCODED offsets: offE = (off&1) ? off + NIMG - 1 : off.
// (verified r11-r12)
__global__ __launch_bounds__(256) void addr_kernel(int* __restrict__ otH,
                                                   int* __restrict__ otD) {
    int idx = blockIdx.x * 256 + threadIdx.x;   // grid = 8*292*32/256 = 292
    int h = idx / (K2P * 32);
    int rem = idx - h * (K2P * 32);
    int n1 = rem >> 5, i = rem & 31;
    int offE = 0;
    if (n1 < K2) {
        int j = n1 * 256 + h * 32 + i;
        int c = j / K2;
        int p = j - c * K2;
        int dr = p / KW;
        int off = c * HP2 + dr * HP + (p - dr * KW);
        offE = (off & 1) ? (off + NIMG - 1) : off;
        otH[(h * K2 + n1) * 32 + i] = offE;
    }
    otD[(h * 32 + i) * K2P + n1] = offE;
}

// Build shifted copies: Ks[i] = K[i+1], Vs[i] = V[i+1].  (verified r11-r12)
__global__ __launch_bounds__(256) void shift_kernel(unsigned int* __restrict__ ka) {
    int j = blockIdx.x * 256 + threadIdx.x;          // 0 .. 2*NIMGU-1
    unsigned int* img = ka + ((j < NIMGU) ? 0 : (2 * NIMGU));
    int jj = (j < NIMGU) ? j : (j - NIMGU);
    unsigned int lo = img[jj];
    unsigned int hi = (jj + 1 < NIMGU) ? img[jj + 1] : 0u;
    img[NIMGU + jj] = (lo >> 16) | (hi << 16);
}

__device__ __forceinline__ float2 gload(const __half* img, int idx) {
    __half2 hv = *reinterpret_cast<const __half2*>(img + idx);
    return make_float2(__low2float(hv), __high2float(hv));
}

// qkv: q (scaled) -> qT[m][l] f32;  k/v -> fp16 padded images  (verified r4-r15)
__global__ __launch_bounds__(256) void qkv_gemm(const float* __restrict__ x,
                                                const float* __restrict__ w,
                                                const float* __restrict__ bias,
                                                float* __restrict__ qT,
                                                __half* __restrict__ kimg,
                                                __half* __restrict__ vimg) {
    __shared__ float As[16][68];  // A[c][l]
    __shared__ float Bs[16][68];  // B[c][oc]
    const int l0 = blockIdx.x * 64;
    const int oc0 = blockIdx.y * 64;
    const int tid = threadIdx.x;
    const int tx = tid & 15;   // oc quad
    const int ty = tid >> 4;   // l quad
    float acc[4][4] = {};
    for (int c0 = 0; c0 < C; c0 += 16) {
#pragma unroll
        for (int i = 0; i < 4; ++i) {
            int idx = i * 256 + tid;
            int cc = idx >> 6, ll = idx & 63;
            As[cc][ll] = x[(c0 + cc) * L + l0 + ll];
        }
#pragma unroll
        for (int i = 0; i < 4; ++i) {
            int idx = i * 256 + tid;
            int cc = idx & 15, oo = idx >> 4;
            Bs[cc][oo] = w[(oc0 + oo) * C + c0 + cc];
        }
        __syncthreads();
#pragma unroll
        for (int kk = 0; kk < 16; ++kk) {
            float4 a = *(const float4*)&As[kk][ty * 4];
            float4 b = *(const float4*)&Bs[kk][tx * 4];
            float av[4] = {a.x, a.y, a.z, a.w};
            float bv[4] = {b.x, b.y, b.z, b.w};
#pragma unroll
            for (int i = 0; i < 4; ++i)
#pragma unroll
                for (int j = 0; j < 4; ++j)
                    acc[i][j] = fmaf(av[i], bv[j], acc[i][j]);
        }
        __syncthreads();
    }
    const int lbase = l0 + ty * 4;
    const int ocbase = oc0 + tx * 4;
    if (oc0 < 256) {
#pragma unroll
        for (int j = 0; j < 4; ++j) {
            int oc = ocbase + j;
            float b = bias[oc];
            float4 v = make_float4((acc[0][j] + b) * SCALE, (acc[1][j] + b) * SCALE,
                                   (acc[2][j] + b) * SCALE, (acc[3][j] + b) * SCALE);
            *(float4*)&qT[oc * L + lbase] = v;
        }
    } else {
        __half* dst = (oc0 < 512) ? kimg : vimg;
        const int cb = ocbase - ((oc0 < 512) ? 256 : 512);
#pragma unroll
        for (int i = 0; i < 4; ++i) {
            int l = lbase + i;
            int r = l / HW, s = l % HW;
            int base = (r + 8) * HP + (s + 8);
#pragma unroll
            for (int j = 0; j < 4; ++j)
                dst[(cb + j) * HP2 + base] = __float2half(acc[i][j] + bias[ocbase + j]);
        }
    }
}

// Fused attention with n1-range split (flash-style 2-block softmax).
// Grid 800: wgid = swizzle(bid); half = wgid&1, h = (wgid>>1)&7, chunk = wgid>>4.
// Each block: r12 lane geometry (16 pairs x 4 slots), n1 in [base, base+cnt).
// Writes UNNORMALIZED partial PV (opart) + per-(h,n) (localmax, localsum) (msb).
__global__ __launch_bounds__(512) void attn_fused(const float* __restrict__ qT,
                                                  const __half* __restrict__ kAll,
                                                  const __half* __restrict__ vAll,
                                                  const int* __restrict__ otH,
                                                  const int* __restrict__ otD,
                                                  float* __restrict__ opart,
                                                  float2* __restrict__ msb) {
    __shared__ float Plds[145 * NT];    // 18560 B
    __shared__ float red[16 * NT];      // 2048 B
    __shared__ float colmax[NT];
    const int bid = blockIdx.x;
    const int wgid = (bid & 7) * 100 + (bid >> 3);
    const int half = wgid & 1;
    const int h = (wgid >> 1) & 7;
    const int n0 = (wgid >> 4) * NT;
    const int base = half ? 144 : 0;
    const int cnt = half ? 145 : 144;
    const int tid = threadIdx.x;
    const int w = tid >> 6, nl = tid & 63;
    const int q4 = nl >> 4, ln = nl & 15;
    const int4* otHq = (const int4*)(otH + h * (K2 * 32));

    // ---- phase B (r12 geometry: 4 rounds x 32 slots + tail range) ----
    {
        const int slot = w * 4 + q4;                      // 0..31
        const int npb = n0 + 2 * ln;                      // even
        const int base2 = (npb / HW) * HP + (npb % HW);   // even
        float2 qp[16];
        for (int pass = 0; pass < 2; ++pass) {
#pragma unroll
            for (int k = 0; k < 16; ++k)
                qp[k] = *(const float2*)&qT[(h * 32 + pass * 16 + k) * L + npb];
            auto doB = [&](int n1l) {
                const int n1 = base + n1l;
                float c0 = 0.f, c1 = 0.f, d0 = 0.f, d1 = 0.f;
#pragma unroll
                for (int k4 = 0; k4 < 4; ++k4) {
                    int4 o = otHq[n1 * 8 + pass * 4 + k4];
                    float2 v0 = gload(kAll, o.x + base2);
                    float2 v1 = gload(kAll, o.y + base2);
                    float2 v2 = gload(kAll, o.z + base2);
                    float2 v3 = gload(kAll, o.w + base2);
                    c0 = fmaf(qp[k4 * 4 + 0].x, v0.x, c0);
                    c1 = fmaf(qp[k4 * 4 + 0].y, v0.y, c1);
                    d0 = fmaf(qp[k4 * 4 + 1].x, v1.x, d0);
                    d1 = fmaf(qp[k4 * 4 + 1].y, v1.y, d1);
                    c0 = fmaf(qp[k4 * 4 + 2].x, v2.x, c0);
                    c1 = fmaf(qp[k4 * 4 + 2].y, v2.y, c1);
                    d0 = fmaf(qp[k4 * 4 + 3].x, v3.x, d0);
                    d1 = fmaf(qp[k4 * 4 + 3].y, v3.y, d1);
                }
                float2* pp = (float2*)&Plds[n1l * NT + 2 * ln];
                if (pass == 0) {
                    *pp = make_float2(c0 + d0, c1 + d1);
                } else {
                    float2 old = *pp;
                    *pp = make_float2(old.x + c0 + d0, old.y + c1 + d1);
                }
            };
#pragma unroll 2
            for (int r = 0; r < 4; ++r) doB(r * 32 + slot);
            if (slot < cnt - 128) doB(128 + slot);
        }
    }
    __syncthreads();

    // ---- phase C: per-column LOCAL softmax stats; mask post (faithful) ----
    {
        const int col = tid & 31, seg = tid >> 5;   // 16 segments
        float mx = -1e30f;
        for (int i = seg; i < cnt; i += 16) mx = fmaxf(mx, Plds[i * NT + col]);
        red[seg * NT + col] = mx;
        __syncthreads();
        if (tid < NT) {
            float m = red[tid];
            for (int s = 1; s < 16; ++s) m = fmaxf(m, red[s * NT + tid]);
            colmax[tid] = m;
        }
        __syncthreads();
        const int ncn = n0 + col;
        const int nr = ncn / HW, nc = ncn % HW;
        const float mxc = colmax[col];
        float s = 0.f;
        for (int i = seg; i < cnt; i += 16) {
            float e = __expf(Plds[i * NT + col] - mxc);
            s += e;
            int n1 = base + i;
            int dr = n1 / KW, ds = n1 - dr * KW;
            unsigned rr = (unsigned)(nr + dr - 8), ss = (unsigned)(nc + ds - 8);
            Plds[i * NT + col] = (rr < HW && ss < HW) ? e : 0.f;
        }
        red[seg * NT + col] = s;
        __syncthreads();
        if (tid < NT) {
            float t = 0.f;
            for (int s2 = 0; s2 < 16; ++s2) t += red[s2 * NT + tid];
            msb[(half * 8 + h) * L + n0 + tid] = make_float2(colmax[tid], t);
        }
        __syncthreads();
    }

    // ---- phase D (r12 geometry): 36 int4 iters + half1 tail; raw partials ----
    {
        const int mq = w * 4 + q4;
        const int npb = n0 + 2 * ln;
        const int base2 = (npb / HW) * HP + (npb % HW);
        const int* otDm = otD + (h * 32 + mq) * K2P + base;  // base%4==0, aligned
        float a0 = 0.f, a1 = 0.f, a2 = 0.f, a3 = 0.f;
        float b0 = 0.f, b1 = 0.f, b2 = 0.f, b3 = 0.f;
#pragma unroll 4
        for (int t4 = 0; t4 < 36; ++t4) {
            const int nb = t4 * 4;
            int4 o = *(const int4*)(otDm + nb);
            float2 p0 = *(const float2*)&Plds[(nb + 0) * NT + 2 * ln];
            float2 p1 = *(const float2*)&Plds[(nb + 1) * NT + 2 * ln];
            float2 p2 = *(const float2*)&Plds[(nb + 2) * NT + 2 * ln];
            float2 p3 = *(const float2*)&Plds[(nb + 3) * NT + 2 * ln];
            float2 v0 = gload(vAll, o.x + base2);
            float2 v1 = gload(vAll, o.y + base2);
            float2 v2 = gload(vAll, o.z + base2);
            float2 v3 = gload(vAll, o.w + base2);
            a0 = fmaf(p0.x, v0.x, a0); b0 = fmaf(p0.y, v0.y, b0);
            a1 = fmaf(p1.x, v1.x, a1); b1 = fmaf(p1.y, v1.y, b1);
            a2 = fmaf(p2.x, v2.x, a2); b2 = fmaf(p2.y, v2.y, b2);
            a3 = fmaf(p3.x, v3.x, a3); b3 = fmaf(p3.y, v3.y, b3);
        }
        if (half) {   // tail local 144 = absolute n1 288
            float2 p = *(const float2*)&Plds[144 * NT + 2 * ln];
            float2 v = gload(vAll, otDm[144] + base2);
            a0 = fmaf(p.x, v.x, a0); b0 = fmaf(p.y, v.y, b0);
        }
        float accA = (a0 + a1) + (a2 + a3);
        float accB = (b0 + b1) + (b2 + b3);
        *(float2*)&opart[(half * 256 + h * 32 + mq) * L + npb] =
            make_float2(accA, accB);
    }
}

// Merge the two n1-halves: out = (w0*o0 + w1*o1) / (w0*s0 + w1*s1).
__global__ __launch_bounds__(256) void merge_kernel(const float* __restrict__ opart,
                                                    const float2* __restrict__ msb,
                                                    float* __restrict__ outT) {
    const int m = blockIdx.x;
    const int h = m >> 5;
    const int n = blockIdx.y * 256 + threadIdx.x;
    if (n >= L) return;
    float2 ms0 = msb[h * L + n];
    float2 ms1 = msb[(8 + h) * L + n];
    float M = fmaxf(ms0.x, ms1.x);
    float w0 = __expf(ms0.x - M), w1 = __expf(ms1.x - M);
    float inv = 1.f / fmaf(w0, ms0.y, w1 * ms1.y);
    float o0 = opart[m * L + n];
    float o1 = opart[(256 + m) * L + n];
    outT[m * L + n] = fmaf(w0, o0, w1 * o1) * inv;
}

// out[oc*1600 + l] = sum_c outT[c][l] * w[oc, c] + b[oc]   (verified r4/r7-r15)
__global__ __launch_bounds__(256) void proj_gemm(const float* __restrict__ aT,
                                                 const float* __restrict__ w,
                                                 const float* __restrict__ bias,
                                                 float* __restrict__ out) {
    __shared__ float As[16][68];  // A[c][l]
    __shared__ float Bs[16][68];  // B[c][oc]
    const int l0 = blockIdx.x * 64;
    const int oc0 = blockIdx.y * 64;
    const int tid = threadIdx.x;
    const int tx = tid & 15;   // oc quad
    const int ty = tid >> 4;   // l quad
    float acc[4][4] = {};      // [i: l][j: oc]
    for (int c0 = 0; c0 < C; c0 += 16) {
#pragma unroll
        for (int i = 0; i < 4; ++i) {
            int idx = i * 256 + tid;
            int cc = idx >> 6, ll = idx & 63;
            As[cc][ll] = aT[(c0 + cc) * L + l0 + ll];
        }
#pragma unroll
        for (int i = 0; i < 4; ++i) {
            int idx = i * 256 + tid;
            int cc = idx & 15, oo = idx >> 4;
            Bs[cc][oo] = w[(oc0 + oo) * C + c0 + cc];
        }
        __syncthreads();
#pragma unroll
        for (int kk = 0; kk < 16; ++kk) {
            float4 a = *(const float4*)&As[kk][ty * 4];
            float4 b = *(const float4*)&Bs[kk][tx * 4];
            float av[4] = {a.x, a.y, a.z, a.w};
            float bv[4] = {b.x, b.y, b.z, b.w};
#pragma unroll
            for (int i = 0; i < 4; ++i)
#pragma unroll
                for (int j = 0; j < 4; ++j)
                    acc[i][j] = fmaf(av[i], bv[j], acc[i][j]);
        }
        __syncthreads();
    }
    const int lbase = l0 + ty * 4;
#pragma unroll
    for (int j = 0; j < 4; ++j) {
        int oc = oc0 + tx * 4 + j;
        float bp = bias[oc];
        float4 v = make_float4(acc[0][j] + bp, acc[1][j] + bp,
                               acc[2][j] + bp, acc[3][j] + bp);
        *(float4*)&out[oc * L + lbase] = v;
    }
}

extern "C" void kernel_launch(void* const* d_in, const int* in_sizes, int n_in,
                              void* d_out, int out_size, void* d_ws, size_t ws_size,
                              hipStream_t stream) {
    const float* x      = (const float*)d_in[0];
    const float* w_qkv  = (const float*)d_in[1];
    const float* b_qkv  = (const float*)d_in[2];
    const float* w_proj = (const float*)d_in[3];
    const float* b_proj = (const float*)d_in[4];
    float* out = (float*)d_out;
    float* ws = (float*)d_ws;
    int*    otH   = (int*)(ws + OFF_TH);
    int*    otD   = (int*)(ws + OFF_TD);
    float*  qT    = ws + OFF_QT;   // reused as outT (disjoint lifetimes)
    __half* kAll  = (__half*)(ws + OFF_KA);
    __half* vAll  = (__half*)(ws + OFF_VA);
    float*  opart = ws + OFF_OP;
    float2* msb   = (float2*)(ws + OFF_MS);

    // zero K/V base+shift images (contiguous: 2 * 802816 floats worth)
    hipMemsetAsync(kAll, 0, (size_t)2 * 802816 * sizeof(float), stream);
    addr_kernel<<<292, 256, 0, stream>>>(otH, otD);

    qkv_gemm<<<dim3(25, 12), 256, 0, stream>>>(x, w_qkv, b_qkv, qT, kAll, vAll);
    shift_kernel<<<(2 * NIMGU) / 256, 256, 0, stream>>>((unsigned int*)kAll);
    attn_fused<<<800, 512, 0, stream>>>(qT, kAll, vAll, otH, otD, opart, msb);
    merge_kernel<<<dim3(256, 7), 256, 0, stream>>>(opart, msb, qT);
    proj_gemm<<<dim3(25, 4), 256, 0, stream>>>(qT, w_proj, b_proj, out);
}

// Round 17
// 97.729 us; speedup vs baseline: 1.3027x; 1.1306x over previous
//
#include <hip/hip_runtime.h>
#include <hip/hip_fp16.h>

#define L 1600
#define C 256
#define HW 40
#define HP 56            // padded spatial (40 + 2*8)
#define HP2 (HP * HP)    // 3136
#define KW 17
#define K2 289
#define K2P 292          // K2 padded to multiple of 4 (int4 loads)
#define HEADS 8
#define NT 32            // n-columns per attn block (16 pairs)
#define NIMG 802816      // halves per padded image (256*3136)
#define SCALE 0.17677669529663687f  // 32^-0.5

// workspace layout (float slots); qT reused as outT (disjoint lifetimes)
// kAll = [K image | K shifted-by-1 copy]; vAll = [V image | V shifted copy]
#define OFF_TH 0                         // otH: 8*289*32 ints = 73984
#define OFF_TD 73984                     // otD: 8*32*292 ints = 74752
#define OFF_QT 148736                    // qT/outT: 409600 f
#define OFF_KA 558336                    // kAll: 2*802816 halves = 802816 f
#define OFF_VA 1361152                   // vAll: 802816 f

// Tables with PARITY-ENCODED offsets: offE = (off&1) ? off + NIMG - 1 : off.
// Reading __half2 at (offE + even_base) is always 4B-aligned; odd offsets are
// served by the shifted copy so the pair (n, n+1) is still correct. (r11-r12)
__global__ __launch_bounds__(256) void addr_kernel(int* __restrict__ otH,
                                                   int* __restrict__ otD) {
    int idx = blockIdx.x * 256 + threadIdx.x;   // grid = 8*292*32/256 = 292
    int h = idx / (K2P * 32);
    int rem = idx - h * (K2P * 32);
    int n1 = rem >> 5, i = rem & 31;
    int offE = 0;
    if (n1 < K2) {
        int j = n1 * 256 + h * 32 + i;
        int c = j / K2;
        int p = j - c * K2;
        int dr = p / KW;
        int off = c * HP2 + dr * HP + (p - dr * KW);
        offE = (off & 1) ? (off + NIMG - 1) : off;
        otH[(h * K2 + n1) * 32 + i] = offE;
    }
    otD[(h * 32 + i) * K2P + n1] = offE;
}

__device__ __forceinline__ float2 gload(const __half* img, int idx) {
    __half2 hv = *reinterpret_cast<const __half2*>(img + idx);
    return make_float2(__low2float(hv), __high2float(hv));
}

// qkv, 32x64 tiles (grid 600 = 2.3 blocks/CU): q (scaled) -> qT[m][l] f32;
// k/v -> fp16 padded images, BOTH copies (base + shifted-by-1) written here.
__global__ __launch_bounds__(256) void qkv_gemm(const float* __restrict__ x,
                                                const float* __restrict__ w,
                                                const float* __restrict__ bias,
                                                float* __restrict__ qT,
                                                __half* __restrict__ kimg,
                                                __half* __restrict__ vimg) {
    __shared__ float As[16][36];  // A[c][l], 32 + pad
    __shared__ float Bs[16][68];  // B[c][oc], 64 + pad
    const int l0 = blockIdx.x * 32;
    const int oc0 = blockIdx.y * 64;
    const int tid = threadIdx.x;
    const int tx = tid & 15;   // oc quad
    const int ty = tid >> 4;   // l pair
    float acc[2][4] = {};
    for (int c0 = 0; c0 < C; c0 += 16) {
#pragma unroll
        for (int i = 0; i < 2; ++i) {
            int idx = i * 256 + tid;
            int cc = idx >> 5, ll = idx & 31;
            As[cc][ll] = x[(c0 + cc) * L + l0 + ll];
        }
#pragma unroll
        for (int i = 0; i < 4; ++i) {
            int idx = i * 256 + tid;
            int cc = idx & 15, oo = idx >> 4;
            Bs[cc][oo] = w[(oc0 + oo) * C + c0 + cc];
        }
        __syncthreads();
#pragma unroll
        for (int kk = 0; kk < 16; ++kk) {
            float2 a = *(const float2*)&As[kk][ty * 2];
            float4 b = *(const float4*)&Bs[kk][tx * 4];
            float av[2] = {a.x, a.y};
            float bv[4] = {b.x, b.y, b.z, b.w};
#pragma unroll
            for (int i = 0; i < 2; ++i)
#pragma unroll
                for (int j = 0; j < 4; ++j)
                    acc[i][j] = fmaf(av[i], bv[j], acc[i][j]);
        }
        __syncthreads();
    }
    const int lbase = l0 + ty * 2;
    const int ocbase = oc0 + tx * 4;
    if (oc0 < 256) {
#pragma unroll
        for (int j = 0; j < 4; ++j) {
            int oc = ocbase + j;
            float b = bias[oc];
            float2 v = make_float2((acc[0][j] + b) * SCALE, (acc[1][j] + b) * SCALE);
            *(float2*)&qT[oc * L + lbase] = v;
        }
    } else {
        __half* dst = (oc0 < 512) ? kimg : vimg;
        const int cb = ocbase - ((oc0 < 512) ? 256 : 512);
#pragma unroll
        for (int i = 0; i < 2; ++i) {
            int l = lbase + i;
            int r = l / HW, s = l % HW;
            int base = (r + 8) * HP + (s + 8);
#pragma unroll
            for (int j = 0; j < 4; ++j) {
                __half hv = __float2half(acc[i][j] + bias[ocbase + j]);
                int idx = (cb + j) * HP2 + base;
                dst[idx] = hv;
                dst[NIMG + idx - 1] = hv;   // shifted copy: s1[i] = img[i+1]
            }
        }
    }
}

// Fused attention (r12 verified, 52 us): NT=32 cols, 512 thr, grid 400 with
// bijective XCD swizzle. Every gather is a __half2 = 2 consecutive n.
__global__ __launch_bounds__(512) void attn_fused(const float* __restrict__ qT,
                                                  const __half* __restrict__ kAll,
                                                  const __half* __restrict__ vAll,
                                                  const int* __restrict__ otH,
                                                  const int* __restrict__ otD,
                                                  float* __restrict__ outT) {
    __shared__ float Plds[K2 * NT];     // 36992 B
    __shared__ float red[16 * NT];      // 2048 B
    __shared__ float colmax[NT], invl[NT];
    const int bid = blockIdx.x;
    const int wgid = (bid & 7) * 50 + (bid >> 3);
    const int h = wgid & 7;
    const int n0 = (wgid >> 3) * NT;
    const int tid = threadIdx.x;
    const int w = tid >> 6, nl = tid & 63;
    const int q4 = nl >> 4, ln = nl & 15;
    const int npb = n0 + 2 * ln;                       // even
    const int base2 = (npb / HW) * HP + (npb % HW);    // even
    const int4* otHq = (const int4*)(otH + h * (K2 * 32));

    // phase B: two 16-channel passes accumulate logits into Plds.
    float2 qp[16];
    for (int pass = 0; pass < 2; ++pass) {
#pragma unroll
        for (int k = 0; k < 16; ++k)
            qp[k] = *(const float2*)&qT[(h * 32 + pass * 16 + k) * L + npb];
        auto doB = [&](int n1) {
            float c0 = 0.f, c1 = 0.f, d0 = 0.f, d1 = 0.f;
#pragma unroll
            for (int k4 = 0; k4 < 4; ++k4) {
                int4 o = otHq[n1 * 8 + pass * 4 + k4];
                float2 v0 = gload(kAll, o.x + base2);
                float2 v1 = gload(kAll, o.y + base2);
                float2 v2 = gload(kAll, o.z + base2);
                float2 v3 = gload(kAll, o.w + base2);
                c0 = fmaf(qp[k4 * 4 + 0].x, v0.x, c0);
                c1 = fmaf(qp[k4 * 4 + 0].y, v0.y, c1);
                d0 = fmaf(qp[k4 * 4 + 1].x, v1.x, d0);
                d1 = fmaf(qp[k4 * 4 + 1].y, v1.y, d1);
                c0 = fmaf(qp[k4 * 4 + 2].x, v2.x, c0);
                c1 = fmaf(qp[k4 * 4 + 2].y, v2.y, c1);
                d0 = fmaf(qp[k4 * 4 + 3].x, v3.x, d0);
                d1 = fmaf(qp[k4 * 4 + 3].y, v3.y, d1);
            }
            float2* pp = (float2*)&Plds[n1 * NT + 2 * ln];
            if (pass == 0) {
                *pp = make_float2(c0 + d0, c1 + d1);
            } else {
                float2 old = *pp;
                *pp = make_float2(old.x + c0 + d0, old.y + c1 + d1);
            }
        };
#pragma unroll 3
        for (int r = 0; r < 9; ++r) doB(r * 32 + w * 4 + q4);
        if (w * 4 + q4 == 0) doB(288);
    }
    __syncthreads();

    // phase C: per-column softmax over n1; sum pre-mask, mask post (faithful).
    {
        const int col = tid & 31, seg = tid >> 5;   // 16 segs
        float mx = -1e30f;
        for (int n1 = seg; n1 < K2; n1 += 16) mx = fmaxf(mx, Plds[n1 * NT + col]);
        red[seg * NT + col] = mx;
        __syncthreads();
        if (tid < NT) {
            float m = red[tid];
            for (int s = 1; s < 16; ++s) m = fmaxf(m, red[s * NT + tid]);
            colmax[tid] = m;
        }
        __syncthreads();
        const int ncn = n0 + col;
        const int nr = ncn / HW, nc = ncn % HW;
        const float mxc = colmax[col];
        float s = 0.f;
        for (int n1 = seg; n1 < K2; n1 += 16) {
            float e = __expf(Plds[n1 * NT + col] - mxc);
            s += e;
            int dr = n1 / KW, ds = n1 - dr * KW;
            unsigned rr = (unsigned)(nr + dr - 8), ss = (unsigned)(nc + ds - 8);
            Plds[n1 * NT + col] = (rr < HW && ss < HW) ? e : 0.f;
        }
        red[seg * NT + col] = s;
        __syncthreads();
        if (tid < NT) {
            float t = 0.f;
            for (int s2 = 0; s2 < 16; ++s2) t += red[s2 * NT + tid];
            invl[tid] = 1.f / t;
        }
        __syncthreads();
    }

    // phase D: lane = (channel mq = w*4+q4, pair ln). n1 wave-uniform ->
    // P reads are LDS float2 broadcasts; offsets via transposed table (int4/4 n1).
    {
        const int mq = w * 4 + q4;
        const int* otDm = otD + (h * 32 + mq) * K2P;
        float a0 = 0.f, a1 = 0.f, a2 = 0.f, a3 = 0.f;
        float b0 = 0.f, b1 = 0.f, b2 = 0.f, b3 = 0.f;
#pragma unroll 4
        for (int t = 0; t < 72; ++t) {
            int4 o = *(const int4*)(otDm + t * 4);
            float2 p0 = *(const float2*)&Plds[(t * 4 + 0) * NT + 2 * ln];
            float2 p1 = *(const float2*)&Plds[(t * 4 + 1) * NT + 2 * ln];
            float2 p2 = *(const float2*)&Plds[(t * 4 + 2) * NT + 2 * ln];
            float2 p3 = *(const float2*)&Plds[(t * 4 + 3) * NT + 2 * ln];
            float2 v0 = gload(vAll, o.x + base2);
            float2 v1 = gload(vAll, o.y + base2);
            float2 v2 = gload(vAll, o.z + base2);
            float2 v3 = gload(vAll, o.w + base2);
            a0 = fmaf(p0.x, v0.x, a0); b0 = fmaf(p0.y, v0.y, b0);
            a1 = fmaf(p1.x, v1.x, a1); b1 = fmaf(p1.y, v1.y, b1);
            a2 = fmaf(p2.x, v2.x, a2); b2 = fmaf(p2.y, v2.y, b2);
            a3 = fmaf(p3.x, v3.x, a3); b3 = fmaf(p3.y, v3.y, b3);
        }
        {   // tail n1 = 288
            float2 p = *(const float2*)&Plds[288 * NT + 2 * ln];
            float2 v = gload(vAll, otDm[288] + base2);
            a0 = fmaf(p.x, v.x, a0); b0 = fmaf(p.y, v.y, b0);
        }
        float accA = (a0 + a1) + (a2 + a3);
        float accB = (b0 + b1) + (b2 + b3);
        float2 ov = make_float2(accA * invl[2 * ln], accB * invl[2 * ln + 1]);
        *(float2*)&outT[(h * 32 + mq) * L + npb] = ov;
    }
}

// proj, 32x64 tiles (grid 200): out[oc*1600+l] = sum_c outT[c][l]*w[oc,c] + b[oc]
__global__ __launch_bounds__(256) void proj_gemm(const float* __restrict__ aT,
                                                 const float* __restrict__ w,
                                                 const float* __restrict__ bias,
                                                 float* __restrict__ out) {
    __shared__ float As[16][36];  // A[c][l], 32 + pad
    __shared__ float Bs[16][68];  // B[c][oc], 64 + pad
    const int l0 = blockIdx.x * 32;
    const int oc0 = blockIdx.y * 64;
    const int tid = threadIdx.x;
    const int tx = tid & 15;   // oc quad
    const int ty = tid >> 4;   // l pair
    float acc[2][4] = {};      // [i: l][j: oc]
    for (int c0 = 0; c0 < C; c0 += 16) {
#pragma unroll
        for (int i = 0; i < 2; ++i) {
            int idx = i * 256 + tid;
            int cc = idx >> 5, ll = idx & 31;
            As[cc][ll] = aT[(c0 + cc) * L + l0 + ll];
        }
#pragma unroll
        for (int i = 0; i < 4; ++i) {
            int idx = i * 256 + tid;
            int cc = idx & 15, oo = idx >> 4;
            Bs[cc][oo] = w[(oc0 + oo) * C + c0 + cc];
        }
        __syncthreads();
#pragma unroll
        for (int kk = 0; kk < 16; ++kk) {
            float2 a = *(const float2*)&As[kk][ty * 2];
            float4 b = *(const float4*)&Bs[kk][tx * 4];
            float av[2] = {a.x, a.y};
            float bv[4] = {b.x, b.y, b.z, b.w};
#pragma unroll
            for (int i = 0; i < 2; ++i)
#pragma unroll
                for (int j = 0; j < 4; ++j)
                    acc[i][j] = fmaf(av[i], bv[j], acc[i][j]);
        }
        __syncthreads();
    }
    const int lbase = l0 + ty * 2;
#pragma unroll
    for (int j = 0; j < 4; ++j) {
        int oc = oc0 + tx * 4 + j;
        float bp = bias[oc];
        float2 v = make_float2(acc[0][j] + bp, acc[1][j] + bp);
        *(float2*)&out[oc * L + lbase] = v;
    }
}

extern "C" void kernel_launch(void* const* d_in, const int* in_sizes, int n_in,
                              void* d_out, int out_size, void* d_ws, size_t ws_size,
                              hipStream_t stream) {
    const float* x      = (const float*)d_in[0];
    const float* w_qkv  = (const float*)d_in[1];
    const float* b_qkv  = (const float*)d_in[2];
    const float* w_proj = (const float*)d_in[3];
    const float* b_proj = (const float*)d_in[4];
    float* out = (float*)d_out;
    float* ws = (float*)d_ws;
    int*    otH  = (int*)(ws + OFF_TH);
    int*    otD  = (int*)(ws + OFF_TD);
    float*  qT   = ws + OFF_QT;   // reused as outT (disjoint lifetimes)
    __half* kAll = (__half*)(ws + OFF_KA);
    __half* vAll = (__half*)(ws + OFF_VA);

    // zero K/V base+shift images (contiguous: 2 * 802816 floats worth)
    hipMemsetAsync(kAll, 0, (size_t)2 * 802816 * sizeof(float), stream);
    addr_kernel<<<292, 256, 0, stream>>>(otH, otD);

    qkv_gemm<<<dim3(50, 12), 256, 0, stream>>>(x, w_qkv, b_qkv, qT, kAll, vAll);
    attn_fused<<<400, 512, 0, stream>>>(qT, kAll, vAll, otH, otD, qT);
    proj_gemm<<<dim3(50, 4), 256, 0, stream>>>(qT, w_proj, b_proj, out);
}

// Round 18
// 95.046 us; speedup vs baseline: 1.3395x; 1.0282x over previous
//
#include <hip/hip_runtime.h>
#include <hip/hip_fp16.h>

#define L 1600
#define C 256
#define HW 40
#define HP 56            // padded spatial (40 + 2*8)
#define HP2 (HP * HP)    // 3136
#define KW 17
#define K2 289
#define K2P 292          // K2 padded to multiple of 4 (int4 loads)
#define HEADS 8
#define NT 32            // n-columns per attn block (16 pairs)
#define NIMG 802816      // halves per padded image (256*3136)
#define SCALE 0.17677669529663687f  // 32^-0.5

// workspace layout (float slots); qT reused as outT (disjoint lifetimes)
// kAll = [K image | K shifted-by-1 copy]; vAll = [V image | V shifted copy]
#define OFF_TH 0                         // otH: 8*289*32 ints = 73984
#define OFF_TD 73984                     // otD: 8*32*292 ints = 74752
#define OFF_QT 148736                    // qT/outT: 409600 f
#define OFF_KA 558336                    // kAll: 2*802816 halves = 802816 f
#define OFF_VA 1361152                   // vAll: 802816 f

// Tables with PARITY-ENCODED offsets: offE = (off&1) ? off + NIMG - 1 : off.
// Reading __half2 at (offE + even_base) is always 4B-aligned; odd offsets are
// served by the shifted copy so the pair (n, n+1) is still correct. (r11-r12)
__global__ __launch_bounds__(256) void addr_kernel(int* __restrict__ otH,
                                                   int* __restrict__ otD) {
    int idx = blockIdx.x * 256 + threadIdx.x;   // grid = 8*292*32/256 = 292
    int h = idx / (K2P * 32);
    int rem = idx - h * (K2P * 32);
    int n1 = rem >> 5, i = rem & 31;
    int offE = 0;
    if (n1 < K2) {
        int j = n1 * 256 + h * 32 + i;
        int c = j / K2;
        int p = j - c * K2;
        int dr = p / KW;
        int off = c * HP2 + dr * HP + (p - dr * KW);
        offE = (off & 1) ? (off + NIMG - 1) : off;
        otH[(h * K2 + n1) * 32 + i] = offE;
    }
    otD[(h * 32 + i) * K2P + n1] = offE;
}

__device__ __forceinline__ float2 gload(const __half* img, int idx) {
    __half2 hv = *reinterpret_cast<const __half2*>(img + idx);
    return make_float2(__low2float(hv), __high2float(hv));
}

// qkv, 64x64 tiles (r4 structure; lane-major = l for coalesced stores):
// q (scaled) -> qT[m][l] f32; k/v -> fp16 images, BOTH copies, vectorized.
__global__ __launch_bounds__(256) void qkv_gemm(const float* __restrict__ x,
                                                const float* __restrict__ w,
                                                const float* __restrict__ bias,
                                                float* __restrict__ qT,
                                                __half* __restrict__ kimg,
                                                __half* __restrict__ vimg) {
    __shared__ float As[16][68];  // A[c][l]
    __shared__ float Bs[16][68];  // B[c][oc]
    const int l0 = blockIdx.x * 64;
    const int oc0 = blockIdx.y * 64;
    const int tid = threadIdx.x;
    const int ty = tid & 15;   // l quad   (lane-consecutive)
    const int tx = tid >> 4;   // oc quad
    float acc[4][4] = {};      // [i: l][j: oc]
    for (int c0 = 0; c0 < C; c0 += 16) {
#pragma unroll
        for (int i = 0; i < 4; ++i) {
            int idx = i * 256 + tid;
            int cc = idx >> 6, ll = idx & 63;
            As[cc][ll] = x[(c0 + cc) * L + l0 + ll];
        }
#pragma unroll
        for (int i = 0; i < 4; ++i) {
            int idx = i * 256 + tid;
            int cc = idx & 15, oo = idx >> 4;
            Bs[cc][oo] = w[(oc0 + oo) * C + c0 + cc];
        }
        __syncthreads();
#pragma unroll
        for (int kk = 0; kk < 16; ++kk) {
            float4 a = *(const float4*)&As[kk][ty * 4];
            float4 b = *(const float4*)&Bs[kk][tx * 4];
            float av[4] = {a.x, a.y, a.z, a.w};
            float bv[4] = {b.x, b.y, b.z, b.w};
#pragma unroll
            for (int i = 0; i < 4; ++i)
#pragma unroll
                for (int j = 0; j < 4; ++j)
                    acc[i][j] = fmaf(av[i], bv[j], acc[i][j]);
        }
        __syncthreads();
    }
    const int lbase = l0 + ty * 4;     // %4 == 0 -> quad stays in one row
    const int ocbase = oc0 + tx * 4;
    if (oc0 < 256) {
#pragma unroll
        for (int j = 0; j < 4; ++j) {
            int oc = ocbase + j;
            float b = bias[oc];
            float4 v = make_float4((acc[0][j] + b) * SCALE, (acc[1][j] + b) * SCALE,
                                   (acc[2][j] + b) * SCALE, (acc[3][j] + b) * SCALE);
            *(float4*)&qT[oc * L + lbase] = v;
        }
    } else {
        __half* dst = (oc0 < 512) ? kimg : vimg;
        const int cb = ocbase - ((oc0 < 512) ? 256 : 512);
        const int r = lbase / HW, s = lbase % HW;
        const int base = (r + 8) * HP + (s + 8);   // %4 == 0 (56,s,8 all %4==0)
#pragma unroll
        for (int j = 0; j < 4; ++j) {
            float bj = bias[ocbase + j];
            __half h0 = __float2half(acc[0][j] + bj);
            __half h1 = __float2half(acc[1][j] + bj);
            __half h2 = __float2half(acc[2][j] + bj);
            __half h3 = __float2half(acc[3][j] + bj);
            const int idx = (cb + j) * HP2 + base;  // %4 == 0
            *(__half2*)&dst[idx]     = __halves2half2(h0, h1);   // base copy
            *(__half2*)&dst[idx + 2] = __halves2half2(h2, h3);
            dst[NIMG + idx - 1] = h0;                            // shifted copy
            *(__half2*)&dst[NIMG + idx] = __halves2half2(h1, h2);
            dst[NIMG + idx + 2] = h3;
        }
    }
}

// Fused attention (r12 verified, 52 us): NT=32 cols, 512 thr, grid 400 with
// bijective XCD swizzle. Every gather is a __half2 = 2 consecutive n.
__global__ __launch_bounds__(512) void attn_fused(const float* __restrict__ qT,
                                                  const __half* __restrict__ kAll,
                                                  const __half* __restrict__ vAll,
                                                  const int* __restrict__ otH,
                                                  const int* __restrict__ otD,
                                                  float* __restrict__ outT) {
    __shared__ float Plds[K2 * NT];     // 36992 B
    __shared__ float red[16 * NT];      // 2048 B
    __shared__ float colmax[NT], invl[NT];
    const int bid = blockIdx.x;
    const int wgid = (bid & 7) * 50 + (bid >> 3);
    const int h = wgid & 7;
    const int n0 = (wgid >> 3) * NT;
    const int tid = threadIdx.x;
    const int w = tid >> 6, nl = tid & 63;
    const int q4 = nl >> 4, ln = nl & 15;
    const int npb = n0 + 2 * ln;                       // even
    const int base2 = (npb / HW) * HP + (npb % HW);    // even
    const int4* otHq = (const int4*)(otH + h * (K2 * 32));

    // phase B: two 16-channel passes accumulate logits into Plds.
    float2 qp[16];
    for (int pass = 0; pass < 2; ++pass) {
#pragma unroll
        for (int k = 0; k < 16; ++k)
            qp[k] = *(const float2*)&qT[(h * 32 + pass * 16 + k) * L + npb];
        auto doB = [&](int n1) {
            float c0 = 0.f, c1 = 0.f, d0 = 0.f, d1 = 0.f;
#pragma unroll
            for (int k4 = 0; k4 < 4; ++k4) {
                int4 o = otHq[n1 * 8 + pass * 4 + k4];
                float2 v0 = gload(kAll, o.x + base2);
                float2 v1 = gload(kAll, o.y + base2);
                float2 v2 = gload(kAll, o.z + base2);
                float2 v3 = gload(kAll, o.w + base2);
                c0 = fmaf(qp[k4 * 4 + 0].x, v0.x, c0);
                c1 = fmaf(qp[k4 * 4 + 0].y, v0.y, c1);
                d0 = fmaf(qp[k4 * 4 + 1].x, v1.x, d0);
                d1 = fmaf(qp[k4 * 4 + 1].y, v1.y, d1);
                c0 = fmaf(qp[k4 * 4 + 2].x, v2.x, c0);
                c1 = fmaf(qp[k4 * 4 + 2].y, v2.y, c1);
                d0 = fmaf(qp[k4 * 4 + 3].x, v3.x, d0);
                d1 = fmaf(qp[k4 * 4 + 3].y, v3.y, d1);
            }
            float2* pp = (float2*)&Plds[n1 * NT + 2 * ln];
            if (pass == 0) {
                *pp = make_float2(c0 + d0, c1 + d1);
            } else {
                float2 old = *pp;
                *pp = make_float2(old.x + c0 + d0, old.y + c1 + d1);
            }
        };
#pragma unroll 3
        for (int r = 0; r < 9; ++r) doB(r * 32 + w * 4 + q4);
        if (w * 4 + q4 == 0) doB(288);
    }
    __syncthreads();

    // phase C: per-column softmax over n1; sum pre-mask, mask post (faithful).
    {
        const int col = tid & 31, seg = tid >> 5;   // 16 segs
        float mx = -1e30f;
        for (int n1 = seg; n1 < K2; n1 += 16) mx = fmaxf(mx, Plds[n1 * NT + col]);
        red[seg * NT + col] = mx;
        __syncthreads();
        if (tid < NT) {
            float m = red[tid];
            for (int s = 1; s < 16; ++s) m = fmaxf(m, red[s * NT + tid]);
            colmax[tid] = m;
        }
        __syncthreads();
        const int ncn = n0 + col;
        const int nr = ncn / HW, nc = ncn % HW;
        const float mxc = colmax[col];
        float s = 0.f;
        for (int n1 = seg; n1 < K2; n1 += 16) {
            float e = __expf(Plds[n1 * NT + col] - mxc);
            s += e;
            int dr = n1 / KW, ds = n1 - dr * KW;
            unsigned rr = (unsigned)(nr + dr - 8), ss = (unsigned)(nc + ds - 8);
            Plds[n1 * NT + col] = (rr < HW && ss < HW) ? e : 0.f;
        }
        red[seg * NT + col] = s;
        __syncthreads();
        if (tid < NT) {
            float t = 0.f;
            for (int s2 = 0; s2 < 16; ++s2) t += red[s2 * NT + tid];
            invl[tid] = 1.f / t;
        }
        __syncthreads();
    }

    // phase D: lane = (channel mq = w*4+q4, pair ln). n1 wave-uniform ->
    // P reads are LDS float2 broadcasts; offsets via transposed table (int4/4 n1).
    {
        const int mq = w * 4 + q4;
        const int* otDm = otD + (h * 32 + mq) * K2P;
        float a0 = 0.f, a1 = 0.f, a2 = 0.f, a3 = 0.f;
        float b0 = 0.f, b1 = 0.f, b2 = 0.f, b3 = 0.f;
#pragma unroll 4
        for (int t = 0; t < 72; ++t) {
            int4 o = *(const int4*)(otDm + t * 4);
            float2 p0 = *(const float2*)&Plds[(t * 4 + 0) * NT + 2 * ln];
            float2 p1 = *(const float2*)&Plds[(t * 4 + 1) * NT + 2 * ln];
            float2 p2 = *(const float2*)&Plds[(t * 4 + 2) * NT + 2 * ln];
            float2 p3 = *(const float2*)&Plds[(t * 4 + 3) * NT + 2 * ln];
            float2 v0 = gload(vAll, o.x + base2);
            float2 v1 = gload(vAll, o.y + base2);
            float2 v2 = gload(vAll, o.z + base2);
            float2 v3 = gload(vAll, o.w + base2);
            a0 = fmaf(p0.x, v0.x, a0); b0 = fmaf(p0.y, v0.y, b0);
            a1 = fmaf(p1.x, v1.x, a1); b1 = fmaf(p1.y, v1.y, b1);
            a2 = fmaf(p2.x, v2.x, a2); b2 = fmaf(p2.y, v2.y, b2);
            a3 = fmaf(p3.x, v3.x, a3); b3 = fmaf(p3.y, v3.y, b3);
        }
        {   // tail n1 = 288
            float2 p = *(const float2*)&Plds[288 * NT + 2 * ln];
            float2 v = gload(vAll, otDm[288] + base2);
            a0 = fmaf(p.x, v.x, a0); b0 = fmaf(p.y, v.y, b0);
        }
        float accA = (a0 + a1) + (a2 + a3);
        float accB = (b0 + b1) + (b2 + b3);
        float2 ov = make_float2(accA * invl[2 * ln], accB * invl[2 * ln + 1]);
        *(float2*)&outT[(h * 32 + mq) * L + npb] = ov;
    }
}

// proj, 32x64 tiles, lane-major = l (coalesced float2 stores):
// out[oc*1600+l] = sum_c outT[c][l]*w[oc,c] + b[oc]
__global__ __launch_bounds__(256) void proj_gemm(const float* __restrict__ aT,
                                                 const float* __restrict__ w,
                                                 const float* __restrict__ bias,
                                                 float* __restrict__ out) {
    __shared__ float As[16][36];  // A[c][l], 32 + pad
    __shared__ float Bs[16][68];  // B[c][oc], 64 + pad
    const int l0 = blockIdx.x * 32;
    const int oc0 = blockIdx.y * 64;
    const int tid = threadIdx.x;
    const int ty = tid & 15;   // l pair (lane-consecutive)
    const int tx = tid >> 4;   // oc quad
    float acc[2][4] = {};      // [i: l][j: oc]
    for (int c0 = 0; c0 < C; c0 += 16) {
#pragma unroll
        for (int i = 0; i < 2; ++i) {
            int idx = i * 256 + tid;
            int cc = idx >> 5, ll = idx & 31;
            As[cc][ll] = aT[(c0 + cc) * L + l0 + ll];
        }
#pragma unroll
        for (int i = 0; i < 4; ++i) {
            int idx = i * 256 + tid;
            int cc = idx & 15, oo = idx >> 4;
            Bs[cc][oo] = w[(oc0 + oo) * C + c0 + cc];
        }
        __syncthreads();
#pragma unroll
        for (int kk = 0; kk < 16; ++kk) {
            float2 a = *(const float2*)&As[kk][ty * 2];
            float4 b = *(const float4*)&Bs[kk][tx * 4];
            float av[2] = {a.x, a.y};
            float bv[4] = {b.x, b.y, b.z, b.w};
#pragma unroll
            for (int i = 0; i < 2; ++i)
#pragma unroll
                for (int j = 0; j < 4; ++j)
                    acc[i][j] = fmaf(av[i], bv[j], acc[i][j]);
        }
        __syncthreads();
    }
    const int lbase = l0 + ty * 2;
#pragma unroll
    for (int j = 0; j < 4; ++j) {
        int oc = oc0 + tx * 4 + j;
        float bp = bias[oc];
        float2 v = make_float2(acc[0][j] + bp, acc[1][j] + bp);
        *(float2*)&out[oc * L + lbase] = v;
    }
}

extern "C" void kernel_launch(void* const* d_in, const int* in_sizes, int n_in,
                              void* d_out, int out_size, void* d_ws, size_t ws_size,
                              hipStream_t stream) {
    const float* x      = (const float*)d_in[0];
    const float* w_qkv  = (const float*)d_in[1];
    const float* b_qkv  = (const float*)d_in[2];
    const float* w_proj = (const float*)d_in[3];
    const float* b_proj = (const float*)d_in[4];
    float* out = (float*)d_out;
    float* ws = (float*)d_ws;
    int*    otH  = (int*)(ws + OFF_TH);
    int*    otD  = (int*)(ws + OFF_TD);
    float*  qT   = ws + OFF_QT;   // reused as outT (disjoint lifetimes)
    __half* kAll = (__half*)(ws + OFF_KA);
    __half* vAll = (__half*)(ws + OFF_VA);

    // zero K/V base+shift images (contiguous: 2 * 802816 floats worth)
    hipMemsetAsync(kAll, 0, (size_t)2 * 802816 * sizeof(float), stream);
    addr_kernel<<<292, 256, 0, stream>>>(otH, otD);

    qkv_gemm<<<dim3(25, 12), 256, 0, stream>>>(x, w_qkv, b_qkv, qT, kAll, vAll);
    attn_fused<<<400, 512, 0, stream>>>(qT, kAll, vAll, otH, otD, qT);
    proj_gemm<<<dim3(50, 4), 256, 0, stream>>>(qT, w_proj, b_proj, out);
}